// Round 11
// baseline (287.136 us; speedup 1.0000x reference)
//
#include <hip/hip_runtime.h>
#include <hip/hip_bf16.h>
#include <math.h>

#define DIM 1024
#define HID 2048
#define NEXP 8
#define NTOK 1024   // B*T
#define TOPK 2

typedef __attribute__((ext_vector_type(4))) float f32x4;
typedef __attribute__((ext_vector_type(8))) short bf16x8;
typedef __attribute__((ext_vector_type(4))) short bf16x4;

__device__ inline short bf1(float f) {
    union { __hip_bfloat16 b; short s; } u; u.b = __float2bfloat16(f); return u.s;
}
__device__ inline bf16x4 cvt4(f32x4 v) {
    bf16x4 r;
#pragma unroll
    for (int i = 0; i < 4; ++i) r[i] = bf1(v[i]);
    return r;
}
__device__ inline bf16x8 cat8(bf16x4 lo, bf16x4 hi) {
    bf16x8 r;
#pragma unroll
    for (int i = 0; i < 4; ++i) { r[i] = lo[i]; r[i + 4] = hi[i]; }
    return r;
}

// ---------------- router (fused with x->bf16 convert) ----------------
__global__ __launch_bounds__(64) void router_kernel(
    const float* __restrict__ x, const float* __restrict__ rw,
    __hip_bfloat16* __restrict__ xb,
    int* __restrict__ counts, int* __restrict__ slot_list, float* __restrict__ w_list)
{
    int t = blockIdx.x;
    int lane = threadIdx.x;
    const float* xr = x + (size_t)t * DIM;
    f32x4 xv[4];
#pragma unroll
    for (int qq = 0; qq < 4; ++qq) xv[qq] = *(const f32x4*)(xr + qq * 256 + lane * 4);
#pragma unroll
    for (int qq = 0; qq < 4; ++qq)
        *(bf16x4*)(xb + (size_t)t * DIM + qq * 256 + lane * 4) = cvt4(xv[qq]);

    float acc[NEXP];
#pragma unroll
    for (int e = 0; e < NEXP; ++e) {
        const float* rwe = rw + e * DIM;
        f32x4 s4 = (f32x4)(0.f);
#pragma unroll
        for (int qq = 0; qq < 4; ++qq) {
            f32x4 wv = *(const f32x4*)(rwe + qq * 256 + lane * 4);
            s4 += xv[qq] * wv;
        }
        acc[e] = s4[0] + s4[1] + s4[2] + s4[3];
    }
#pragma unroll
    for (int off = 32; off > 0; off >>= 1) {
#pragma unroll
        for (int e = 0; e < NEXP; ++e) acc[e] += __shfl_down(acc[e], off, 64);
    }
    if (lane == 0) {
        int i1 = 0;
#pragma unroll
        for (int e = 1; e < NEXP; ++e) if (acc[e] > acc[i1]) i1 = e;
        int i2 = -1;
#pragma unroll
        for (int e = 0; e < NEXP; ++e) {
            if (e == i1) continue;
            if (i2 < 0 || acc[e] > acc[i2]) i2 = e;
        }
        float w1 = 1.f / (1.f + expf(acc[i2] - acc[i1]));   // softmax renorm over top-2
        float w2 = 1.f - w1;
        int p1 = atomicAdd(&counts[i1], 1);
        slot_list[i1 * NTOK + p1] = t * 2 + 0;
        w_list[i1 * NTOK + p1] = w1;
        int p2 = atomicAdd(&counts[i2], 1);
        slot_list[i2 * NTOK + p2] = t * 2 + 1;
        w_list[i2 * NTOK + p2] = w2;
    }
}

// ---------------- gate+up: µbench-pattern weight staging + barrier-free m-loop ----------------
// Block = (expert e, 16 h-cols). B-panel = G[16 rows] + U[16 rows], each 64KB
// CONTIGUOUS in memory. Each wave streams one 16KB-contiguous span (1KB/instr,
// all loads in flight) -> cvt -> 64KB swizzled LDS. Then barrier-free m-loop:
// A-fragments per-lane direct from xb (2MB -> L2-resident on every XCD),
// B from LDS; 8-kstep register batches double-buffered (16 loads in flight).
__global__ __launch_bounds__(256, 2) void gateup_mfma(
    const __hip_bfloat16* __restrict__ xb, const float* __restrict__ wg,
    const float* __restrict__ wu, const int* __restrict__ counts,
    const int* __restrict__ slot_list, const float* __restrict__ w_list,
    const __hip_bfloat16* __restrict__ zrow, __hip_bfloat16* __restrict__ h_buf)
{
    __shared__ short Bs[32 * 1024];   // 64KB: rows 0-15 G, 16-31 U; slot ^= row&7

    int bid = blockIdx.x;
    int e = bid >> 7;                 // 8 experts x 128 strips
    int hb = (bid & 127) * 16;

    int n_e = counts[e];
    if (n_e == 0) return;
    const int* sl = slot_list + e * NTOK;
    const float* wl = w_list + e * NTOK;

    int tid = threadIdx.x, lane = tid & 63, w = tid >> 6;
    int fr = lane & 15, fq = lane >> 4;

    // ---- B staging: wave w streams G rows [hb+4w, +4) (16KB contiguous), then U ----
    {
        const char* gG = (const char*)(wg + (size_t)e * HID * DIM + (size_t)(hb + 4 * w) * DIM);
        const char* gU = (const char*)(wu + (size_t)e * HID * DIM + (size_t)(hb + 4 * w) * DIM);
        f32x4 lo[8], hi[8];
#pragma unroll
        for (int i = 0; i < 8; ++i) {
            int b = i * 2048 + lane * 32;
            lo[i] = *(const f32x4*)(gG + b); hi[i] = *(const f32x4*)(gG + b + 16);
        }
#pragma unroll
        for (int i = 0; i < 8; ++i) {
            int b = i * 2048 + lane * 32;
            int rl = b >> 12, s = (b & 4095) >> 5, row = 4 * w + rl;
            *(bf16x8*)&Bs[row * 1024 + ((s ^ (row & 7)) * 8)] = cat8(cvt4(lo[i]), cvt4(hi[i]));
        }
#pragma unroll
        for (int i = 0; i < 8; ++i) {
            int b = i * 2048 + lane * 32;
            lo[i] = *(const f32x4*)(gU + b); hi[i] = *(const f32x4*)(gU + b + 16);
        }
#pragma unroll
        for (int i = 0; i < 8; ++i) {
            int b = i * 2048 + lane * 32;
            int rl = b >> 12, s = (b & 4095) >> 5, row = 16 + 4 * w + rl;
            *(bf16x8*)&Bs[row * 1024 + ((s ^ (row & 7)) * 8)] = cat8(cvt4(lo[i]), cvt4(hi[i]));
        }
    }
    __syncthreads();

    // ---- barrier-free m-loop: wave owns 32 token rows (2 groups of 16) ----
#pragma unroll 1
    for (int m0 = 0; m0 < n_e; m0 += 128) {
        int rows = n_e - m0; if (rows > 128) rows = 128;
        const char* pA[2];
#pragma unroll
        for (int rg = 0; rg < 2; ++rg) {
            int r = w * 32 + rg * 16 + fr;
            pA[rg] = (const char*)((r < rows) ? (xb + (size_t)(sl[m0 + r] >> 1) * DIM) : zrow) + fq * 16;
        }
        f32x4 ag[2], au[2];
        ag[0] = ag[1] = (f32x4)(0.f); au[0] = au[1] = (f32x4)(0.f);

        bf16x8 aa[2][2][8];
#pragma unroll
        for (int t = 0; t < 8; ++t) {
            aa[0][0][t] = *(const bf16x8*)(pA[0] + t * 64);
            aa[0][1][t] = *(const bf16x8*)(pA[1] + t * 64);
        }
#pragma unroll
        for (int b = 0; b < 4; ++b) {
            if (b < 3) {
#pragma unroll
                for (int t = 0; t < 8; ++t) {
                    int kt = (b + 1) * 8 + t;
                    aa[(b + 1) & 1][0][t] = *(const bf16x8*)(pA[0] + kt * 64);
                    aa[(b + 1) & 1][1][t] = *(const bf16x8*)(pA[1] + kt * 64);
                }
            }
#pragma unroll
            for (int t = 0; t < 8; ++t) {
                int kt = b * 8 + t;
                int sg = (((kt * 4 + fq) ^ (fr & 7)) * 8);
                bf16x8 bg = *(const bf16x8*)&Bs[fr * 1024 + sg];
                bf16x8 bu = *(const bf16x8*)&Bs[(16 + fr) * 1024 + sg];
                ag[0] = __builtin_amdgcn_mfma_f32_16x16x32_bf16(aa[b & 1][0][t], bg, ag[0], 0, 0, 0);
                ag[1] = __builtin_amdgcn_mfma_f32_16x16x32_bf16(aa[b & 1][1][t], bg, ag[1], 0, 0, 0);
                au[0] = __builtin_amdgcn_mfma_f32_16x16x32_bf16(aa[b & 1][0][t], bu, au[0], 0, 0, 0);
                au[1] = __builtin_amdgcn_mfma_f32_16x16x32_bf16(aa[b & 1][1][t], bu, au[1], 0, 0, 0);
            }
        }

        // epilogue: h = wt * silu(g) * u  (row = w*32+rg*16+fq*4+reg, col = hb+fr)
#pragma unroll
        for (int rg = 0; rg < 2; ++rg)
#pragma unroll
            for (int reg = 0; reg < 4; ++reg) {
                int r = w * 32 + rg * 16 + fq * 4 + reg;
                if (r < rows) {
                    int slot = sl[m0 + r];
                    float wt = wl[m0 + r];
                    float g = ag[rg][reg], u = au[rg][reg];
                    float h = wt * (g / (1.f + expf(-g))) * u;
                    h_buf[(size_t)slot * HID + hb + fr] = __float2bfloat16(h);
                }
            }
    }
}

// ---------------- down: same structure; Wd strip 16 rows x K=2048 ----------------
__global__ __launch_bounds__(256, 2) void down_mfma(
    const __hip_bfloat16* __restrict__ h_buf, const float* __restrict__ wd,
    const int* __restrict__ counts, const int* __restrict__ slot_list,
    const __hip_bfloat16* __restrict__ zrow, float* __restrict__ ybuf)
{
    __shared__ short Bs[16 * 2048];   // 64KB: 16 rows x 2048 bf16; slot ^= row&7

    int bid = blockIdx.x;
    int e = bid >> 6;                 // 8 experts x 64 strips
    int db = (bid & 63) * 16;

    int n_e = counts[e];
    if (n_e == 0) return;
    const int* sl = slot_list + e * NTOK;

    int tid = threadIdx.x, lane = tid & 63, w = tid >> 6;
    int fr = lane & 15, fq = lane >> 4;

    // ---- stage Wd rows [db+4w, +4): 32KB contiguous per wave ----
    {
        const char* gW = (const char*)(wd + (size_t)e * DIM * HID + (size_t)(db + 4 * w) * HID);
#pragma unroll
        for (int g2 = 0; g2 < 2; ++g2) {
            f32x4 lo[8], hi[8];
#pragma unroll
            for (int i = 0; i < 8; ++i) {
                int b = (g2 * 8 + i) * 2048 + lane * 32;
                lo[i] = *(const f32x4*)(gW + b); hi[i] = *(const f32x4*)(gW + b + 16);
            }
#pragma unroll
            for (int i = 0; i < 8; ++i) {
                int b = (g2 * 8 + i) * 2048 + lane * 32;
                int rl = b >> 13, s = (b & 8191) >> 5, row = 4 * w + rl;
                *(bf16x8*)&Bs[row * 2048 + ((s ^ (row & 7)) * 8)] = cat8(cvt4(lo[i]), cvt4(hi[i]));
            }
        }
    }
    __syncthreads();

#pragma unroll 1
    for (int m0 = 0; m0 < n_e; m0 += 128) {
        int rows = n_e - m0; if (rows > 128) rows = 128;
        const char* pA[2];
#pragma unroll
        for (int rg = 0; rg < 2; ++rg) {
            int r = w * 32 + rg * 16 + fr;
            pA[rg] = (const char*)((r < rows) ? (h_buf + (size_t)sl[m0 + r] * HID) : zrow) + fq * 16;
        }
        f32x4 acc[2];
        acc[0] = acc[1] = (f32x4)(0.f);

        bf16x8 aa[2][2][8];
#pragma unroll
        for (int t = 0; t < 8; ++t) {
            aa[0][0][t] = *(const bf16x8*)(pA[0] + t * 64);
            aa[0][1][t] = *(const bf16x8*)(pA[1] + t * 64);
        }
#pragma unroll
        for (int b = 0; b < 8; ++b) {
            if (b < 7) {
#pragma unroll
                for (int t = 0; t < 8; ++t) {
                    int kt = (b + 1) * 8 + t;
                    aa[(b + 1) & 1][0][t] = *(const bf16x8*)(pA[0] + kt * 64);
                    aa[(b + 1) & 1][1][t] = *(const bf16x8*)(pA[1] + kt * 64);
                }
            }
#pragma unroll
            for (int t = 0; t < 8; ++t) {
                int kt = b * 8 + t;
                bf16x8 bw = *(const bf16x8*)&Bs[fr * 2048 + (((kt * 4 + fq) ^ (fr & 7)) * 8)];
                acc[0] = __builtin_amdgcn_mfma_f32_16x16x32_bf16(aa[b & 1][0][t], bw, acc[0], 0, 0, 0);
                acc[1] = __builtin_amdgcn_mfma_f32_16x16x32_bf16(aa[b & 1][1][t], bw, acc[1], 0, 0, 0);
            }
        }

#pragma unroll
        for (int rg = 0; rg < 2; ++rg)
#pragma unroll
            for (int reg = 0; reg < 4; ++reg) {
                int r = w * 32 + rg * 16 + fq * 4 + reg;
                if (r < rows) {
                    int slot = sl[m0 + r];
                    ybuf[(size_t)slot * DIM + db + fr] = acc[rg][reg];
                }
            }
    }
}

// ---------------- combine: out[t] = y[2t] + y[2t+1] ----------------
__global__ __launch_bounds__(256) void combine_kernel(const float* __restrict__ ybuf, float* __restrict__ out)
{
    int i = blockIdx.x * 256 + threadIdx.x;
    int t = i >> 8;
    int c = i & 255;
    const float4* ya = (const float4*)(ybuf + (size_t)(2 * t) * DIM) + c;
    const float4* yb = (const float4*)(ybuf + (size_t)(2 * t + 1) * DIM) + c;
    float4 a = *ya, b = *yb, r;
    r.x = a.x + b.x; r.y = a.y + b.y; r.z = a.z + b.z; r.w = a.w + b.w;
    ((float4*)(out + (size_t)t * DIM))[c] = r;
}

extern "C" void kernel_launch(void* const* d_in, const int* in_sizes, int n_in,
                              void* d_out, int out_size, void* d_ws, size_t ws_size,
                              hipStream_t stream) {
    const float* x  = (const float*)d_in[0];
    const float* rw = (const float*)d_in[1];
    const float* wg = (const float*)d_in[2];
    const float* wu = (const float*)d_in[3];
    const float* wd = (const float*)d_in[4];
    float* out = (float*)d_out;

    char* ws = (char*)d_ws;
    int* counts            = (int*)ws;                                   // 256 B
    int* slot_list         = (int*)(ws + 256);                           // 32 KB
    float* w_list          = (float*)(ws + 256 + NEXP * NTOK * 4);       // 32 KB
    __hip_bfloat16* xb     = (__hip_bfloat16*)(ws + 256 + 2 * NEXP * NTOK * 4);       // 2 MB
    __hip_bfloat16* h_buf  = (__hip_bfloat16*)((char*)xb + (size_t)NTOK * DIM * 2);   // 8 MB
    float* ybuf            = (float*)((char*)h_buf + (size_t)NTOK * TOPK * HID * 2);  // 8 MB
    __hip_bfloat16* zrow   = (__hip_bfloat16*)((char*)ybuf + (size_t)NTOK * TOPK * DIM * 4); // 4 KB zeros

    hipMemsetAsync(counts, 0, NEXP * sizeof(int), stream);
    hipMemsetAsync(zrow, 0, HID * sizeof(__hip_bfloat16), stream);
    router_kernel<<<NTOK, 64, 0, stream>>>(x, rw, xb, counts, slot_list, w_list);
    gateup_mfma<<<1024, 256, 0, stream>>>(xb, wg, wu, counts, slot_list, w_list, zrow, h_buf);
    down_mfma<<<512, 256, 0, stream>>>(h_buf, wd, counts, slot_list, zrow, ybuf);
    combine_kernel<<<NTOK * DIM / 4 / 256, 256, 0, stream>>>(ybuf, out);
}

// Round 12
// 174.763 us; speedup vs baseline: 1.6430x; 1.6430x over previous
//
#include <hip/hip_runtime.h>
#include <hip/hip_bf16.h>
#include <math.h>

#define DIM 1024
#define HID 2048
#define NEXP 8
#define NTOK 1024   // B*T
#define TOPK 2

typedef __attribute__((ext_vector_type(4))) float f32x4;
typedef __attribute__((ext_vector_type(8))) short bf16x8;
typedef __attribute__((ext_vector_type(4))) short bf16x4;

__device__ inline short bf1(float f) {
    union { __hip_bfloat16 b; short s; } u; u.b = __float2bfloat16(f); return u.s;
}
__device__ inline bf16x4 cvt4(f32x4 v) {
    bf16x4 r;
#pragma unroll
    for (int i = 0; i < 4; ++i) r[i] = bf1(v[i]);
    return r;
}
__device__ inline bf16x8 cat8(bf16x4 lo, bf16x4 hi) {
    bf16x8 r;
#pragma unroll
    for (int i = 0; i < 4; ++i) { r[i] = lo[i]; r[i + 4] = hi[i]; }
    return r;
}

// ---------------- wcvt: grid-stride f32 -> bf16 (µbench-identical access pattern) ----------------
// THE PROBE: if this runs at ~5-6 TB/s while the GEMM staging pins at 1.1, the
// "dense read window" theory holds; if it also pins at ~1.1, memory itself is the wall.
__global__ __launch_bounds__(256) void wcvt_kernel(const float* __restrict__ in,
                                                   __hip_bfloat16* __restrict__ outb, int n4)
{
    int stride = gridDim.x * 256;
    for (int i = blockIdx.x * 256 + threadIdx.x; i < n4; i += stride) {
        f32x4 v = *(const f32x4*)(in + (size_t)i * 4);
        *(bf16x4*)(outb + (size_t)i * 4) = cvt4(v);
    }
}

// ---------------- router (fused with x->bf16 convert) ----------------
__global__ __launch_bounds__(64) void router_kernel(
    const float* __restrict__ x, const float* __restrict__ rw,
    __hip_bfloat16* __restrict__ xb,
    int* __restrict__ counts, int* __restrict__ slot_list, float* __restrict__ w_list)
{
    int t = blockIdx.x;
    int lane = threadIdx.x;
    const float* xr = x + (size_t)t * DIM;
    f32x4 xv[4];
#pragma unroll
    for (int qq = 0; qq < 4; ++qq) xv[qq] = *(const f32x4*)(xr + qq * 256 + lane * 4);
#pragma unroll
    for (int qq = 0; qq < 4; ++qq)
        *(bf16x4*)(xb + (size_t)t * DIM + qq * 256 + lane * 4) = cvt4(xv[qq]);

    float acc[NEXP];
#pragma unroll
    for (int e = 0; e < NEXP; ++e) {
        const float* rwe = rw + e * DIM;
        f32x4 s4 = (f32x4)(0.f);
#pragma unroll
        for (int qq = 0; qq < 4; ++qq) {
            f32x4 wv = *(const f32x4*)(rwe + qq * 256 + lane * 4);
            s4 += xv[qq] * wv;
        }
        acc[e] = s4[0] + s4[1] + s4[2] + s4[3];
    }
#pragma unroll
    for (int off = 32; off > 0; off >>= 1) {
#pragma unroll
        for (int e = 0; e < NEXP; ++e) acc[e] += __shfl_down(acc[e], off, 64);
    }
    if (lane == 0) {
        int i1 = 0;
#pragma unroll
        for (int e = 1; e < NEXP; ++e) if (acc[e] > acc[i1]) i1 = e;
        int i2 = -1;
#pragma unroll
        for (int e = 0; e < NEXP; ++e) {
            if (e == i1) continue;
            if (i2 < 0 || acc[e] > acc[i2]) i2 = e;
        }
        float w1 = 1.f / (1.f + expf(acc[i2] - acc[i1]));   // softmax renorm over top-2
        float w2 = 1.f - w1;
        int p1 = atomicAdd(&counts[i1], 1);
        slot_list[i1 * NTOK + p1] = t * 2 + 0;
        w_list[i1 * NTOK + p1] = w1;
        int p2 = atomicAdd(&counts[i2], 1);
        slot_list[i2 * NTOK + p2] = t * 2 + 1;
        w_list[i2 * NTOK + p2] = w2;
    }
}

// ---------------- gate+up: R6 structure, bf16 weights (from wcvt) ----------------
// 64x64x64 tile, swizzled unpadded LDS (48KB -> 3 blocks/CU), 2-step reg prefetch.
// grid 1024 = (p in [0,256)=e*32+hb) x (z in [0,4)); bid=(p&7)+8*(z+4*(p>>3)).
__global__ __launch_bounds__(256) void gateup_mfma(
    const __hip_bfloat16* __restrict__ xb, const __hip_bfloat16* __restrict__ wgb,
    const __hip_bfloat16* __restrict__ wub, const int* __restrict__ counts,
    const int* __restrict__ slot_list, const float* __restrict__ w_list,
    const __hip_bfloat16* __restrict__ zrow, __hip_bfloat16* __restrict__ h_buf)
{
    __shared__ short Xs[2][64 * 64];
    __shared__ short Gs[2][64 * 64];
    __shared__ short Us[2][64 * 64];

    int bid = blockIdx.x;
    int pl = bid & 7, sfold = bid >> 3;
    int z = sfold & 3, ph = sfold >> 2;
    int p = (ph << 3) | pl;              // 0..255
    int e = p >> 5;
    int hbase = (p & 31) * 64;

    int n_e = counts[e];
    if (n_e == 0) return;
    const int* sl = slot_list + e * NTOK;
    const float* wl = w_list + e * NTOK;

    int tid = threadIdx.x;
    int lane = tid & 63;
    int wn = tid >> 6;                   // wave -> 16-col strip
    int fr = lane & 15, fq = lane >> 4;

    int r2 = tid >> 3;                   // staging row 0..31 (and +32)
    int j = tid & 7;                     // 16B chunk in row
    int sw = (j ^ (r2 & 7)) * 8;         // XOR chunk swizzle (write side)

    const __hip_bfloat16* g0 = wgb + (size_t)e * HID * DIM + (size_t)(hbase + r2) * DIM + j * 8;
    const __hip_bfloat16* g1 = g0 + (size_t)32 * DIM;
    const __hip_bfloat16* u0 = wub + (size_t)e * HID * DIM + (size_t)(hbase + r2) * DIM + j * 8;
    const __hip_bfloat16* u1 = u0 + (size_t)32 * DIM;

    for (int m0 = z * 64; m0 < n_e; m0 += 256) {
        int rows = n_e - m0; if (rows > 64) rows = 64;
        const __hip_bfloat16* x0 = (r2 < rows) ? xb + (size_t)(sl[m0 + r2] >> 1) * DIM + j * 8 : zrow + j * 8;
        const __hip_bfloat16* x1 = (r2 + 32 < rows) ? xb + (size_t)(sl[m0 + r2 + 32] >> 1) * DIM + j * 8 : zrow + j * 8;

        f32x4 accg[4], accu[4];
#pragma unroll
        for (int ms = 0; ms < 4; ++ms) { accg[ms] = (f32x4)(0.f); accu[ms] = (f32x4)(0.f); }

        bf16x8 sx[2][2], sg[2][2], su[2][2];
#pragma unroll
        for (int st = 0; st < 2; ++st) {
            int ko = st * 64;
            sx[st][0] = *(const bf16x8*)(x0 + ko);
            sx[st][1] = *(const bf16x8*)(x1 + ko);
            sg[st][0] = *(const bf16x8*)(g0 + ko);
            sg[st][1] = *(const bf16x8*)(g1 + ko);
            su[st][0] = *(const bf16x8*)(u0 + ko);
            su[st][1] = *(const bf16x8*)(u1 + ko);
        }

#pragma unroll 1
        for (int tt = 0; tt < DIM / 64; tt += 2) {
#pragma unroll
            for (int half = 0; half < 2; ++half) {
                *(bf16x8*)&Xs[half][r2 * 64 + sw] = sx[half][0];
                *(bf16x8*)&Xs[half][(r2 + 32) * 64 + sw] = sx[half][1];
                *(bf16x8*)&Gs[half][r2 * 64 + sw] = sg[half][0];
                *(bf16x8*)&Gs[half][(r2 + 32) * 64 + sw] = sg[half][1];
                *(bf16x8*)&Us[half][r2 * 64 + sw] = su[half][0];
                *(bf16x8*)&Us[half][(r2 + 32) * 64 + sw] = su[half][1];
                int k2 = (tt + half + 2) * 64;
                if (k2 < DIM) {
                    sx[half][0] = *(const bf16x8*)(x0 + k2);
                    sx[half][1] = *(const bf16x8*)(x1 + k2);
                    sg[half][0] = *(const bf16x8*)(g0 + k2);
                    sg[half][1] = *(const bf16x8*)(g1 + k2);
                    su[half][0] = *(const bf16x8*)(u0 + k2);
                    su[half][1] = *(const bf16x8*)(u1 + k2);
                }
                __syncthreads();
#pragma unroll
                for (int kk = 0; kk < 2; ++kk) {
                    int co = ((kk * 4 + fq) ^ (fr & 7)) * 8;
                    bf16x8 bg = *(const bf16x8*)&Gs[half][(wn * 16 + fr) * 64 + co];
                    bf16x8 bu = *(const bf16x8*)&Us[half][(wn * 16 + fr) * 64 + co];
#pragma unroll
                    for (int ms = 0; ms < 4; ++ms) {
                        bf16x8 a = *(const bf16x8*)&Xs[half][(ms * 16 + fr) * 64 + co];
                        accg[ms] = __builtin_amdgcn_mfma_f32_16x16x32_bf16(a, bg, accg[ms], 0, 0, 0);
                        accu[ms] = __builtin_amdgcn_mfma_f32_16x16x32_bf16(a, bu, accu[ms], 0, 0, 0);
                    }
                }
                __syncthreads();
            }
        }

        // epilogue: h = w * silu(g) * u -> bf16 (D row = ms*16+fq*4+reg, col = wn*16+fr)
#pragma unroll
        for (int ms = 0; ms < 4; ++ms) {
#pragma unroll
            for (int reg = 0; reg < 4; ++reg) {
                int r = ms * 16 + fq * 4 + reg;
                if (r < rows) {
                    int slot = sl[m0 + r];
                    float w = wl[m0 + r];
                    float g = accg[ms][reg], u = accu[ms][reg];
                    float h = w * (g / (1.f + expf(-g))) * u;
                    h_buf[(size_t)slot * HID + hbase + wn * 16 + fr] = __float2bfloat16(h);
                }
            }
        }
    }
}

// ---------------- down grouped MFMA GEMM (R6 verbatim, f32 wd) ----------------
__global__ __launch_bounds__(256) void down_mfma(
    const __hip_bfloat16* __restrict__ h_buf, const float* __restrict__ wd,
    const int* __restrict__ counts, const int* __restrict__ slot_list,
    const __hip_bfloat16* __restrict__ zrow, float* __restrict__ ybuf)
{
    __shared__ short Hs[2][64 * 64];
    __shared__ short Ws[2][64 * 64];

    int bid = blockIdx.x;
    int pl = bid & 7, sfold = bid >> 3;
    int z = sfold & 3, qh = sfold >> 2;
    int q = (qh << 3) | pl;              // 0..127
    int e = q >> 4;
    int dbase = (q & 15) * 64;

    int n_e = counts[e];
    if (n_e == 0) return;
    const int* sl = slot_list + e * NTOK;
    const float* WD = wd + (size_t)e * DIM * HID;

    int tid = threadIdx.x;
    int lane = tid & 63;
    int wn = tid >> 6;
    int fr = lane & 15, fq = lane >> 4;

    int r2 = tid >> 3;
    int j = tid & 7;
    int sw = (j ^ (r2 & 7)) * 8;

    const float* w0 = WD + (size_t)(dbase + r2) * HID + j * 8;
    const float* w1 = w0 + (size_t)32 * HID;

    for (int m0 = z * 64; m0 < n_e; m0 += 256) {
        int rows = n_e - m0; if (rows > 64) rows = 64;
        const __hip_bfloat16* h0 = (r2 < rows) ? h_buf + (size_t)sl[m0 + r2] * HID + j * 8 : zrow + j * 8;
        const __hip_bfloat16* h1 = (r2 + 32 < rows) ? h_buf + (size_t)sl[m0 + r2 + 32] * HID + j * 8 : zrow + j * 8;

        f32x4 acc[4];
#pragma unroll
        for (int ms = 0; ms < 4; ++ms) acc[ms] = (f32x4)(0.f);

        bf16x8 sh[2][2];
        f32x4 sd[2][4];
#pragma unroll
        for (int st = 0; st < 2; ++st) {
            int ko = st * 64;
            sh[st][0] = *(const bf16x8*)(h0 + ko);
            sh[st][1] = *(const bf16x8*)(h1 + ko);
            sd[st][0] = *(const f32x4*)(w0 + ko);
            sd[st][1] = *(const f32x4*)(w0 + ko + 4);
            sd[st][2] = *(const f32x4*)(w1 + ko);
            sd[st][3] = *(const f32x4*)(w1 + ko + 4);
        }

#pragma unroll 1
        for (int tt = 0; tt < HID / 64; tt += 2) {
#pragma unroll
            for (int half = 0; half < 2; ++half) {
                *(bf16x8*)&Hs[half][r2 * 64 + sw] = sh[half][0];
                *(bf16x8*)&Hs[half][(r2 + 32) * 64 + sw] = sh[half][1];
                *(bf16x8*)&Ws[half][r2 * 64 + sw] = cat8(cvt4(sd[half][0]), cvt4(sd[half][1]));
                *(bf16x8*)&Ws[half][(r2 + 32) * 64 + sw] = cat8(cvt4(sd[half][2]), cvt4(sd[half][3]));
                int k2 = (tt + half + 2) * 64;
                if (k2 < HID) {
                    sh[half][0] = *(const bf16x8*)(h0 + k2);
                    sh[half][1] = *(const bf16x8*)(h1 + k2);
                    sd[half][0] = *(const f32x4*)(w0 + k2);
                    sd[half][1] = *(const f32x4*)(w0 + k2 + 4);
                    sd[half][2] = *(const f32x4*)(w1 + k2);
                    sd[half][3] = *(const f32x4*)(w1 + k2 + 4);
                }
                __syncthreads();
#pragma unroll
                for (int kk = 0; kk < 2; ++kk) {
                    int co = ((kk * 4 + fq) ^ (fr & 7)) * 8;
                    bf16x8 b = *(const bf16x8*)&Ws[half][(wn * 16 + fr) * 64 + co];
#pragma unroll
                    for (int ms = 0; ms < 4; ++ms) {
                        bf16x8 a = *(const bf16x8*)&Hs[half][(ms * 16 + fr) * 64 + co];
                        acc[ms] = __builtin_amdgcn_mfma_f32_16x16x32_bf16(a, b, acc[ms], 0, 0, 0);
                    }
                }
                __syncthreads();
            }
        }

#pragma unroll
        for (int ms = 0; ms < 4; ++ms) {
#pragma unroll
            for (int reg = 0; reg < 4; ++reg) {
                int r = ms * 16 + fq * 4 + reg;
                if (r < rows) {
                    int slot = sl[m0 + r];
                    ybuf[(size_t)slot * DIM + dbase + wn * 16 + fr] = acc[ms][reg];
                }
            }
        }
    }
}

// ---------------- combine: out[t] = y[2t] + y[2t+1] ----------------
__global__ __launch_bounds__(256) void combine_kernel(const float* __restrict__ ybuf, float* __restrict__ out)
{
    int i = blockIdx.x * 256 + threadIdx.x;
    int t = i >> 8;
    int c = i & 255;
    const float4* ya = (const float4*)(ybuf + (size_t)(2 * t) * DIM) + c;
    const float4* yb = (const float4*)(ybuf + (size_t)(2 * t + 1) * DIM) + c;
    float4 a = *ya, b = *yb, r;
    r.x = a.x + b.x; r.y = a.y + b.y; r.z = a.z + b.z; r.w = a.w + b.w;
    ((float4*)(out + (size_t)t * DIM))[c] = r;
}

extern "C" void kernel_launch(void* const* d_in, const int* in_sizes, int n_in,
                              void* d_out, int out_size, void* d_ws, size_t ws_size,
                              hipStream_t stream) {
    const float* x  = (const float*)d_in[0];
    const float* rw = (const float*)d_in[1];
    const float* wg = (const float*)d_in[2];
    const float* wu = (const float*)d_in[3];
    const float* wd = (const float*)d_in[4];
    float* out = (float*)d_out;

    char* ws = (char*)d_ws;
    int* counts            = (int*)ws;                                   // 256 B
    int* slot_list         = (int*)(ws + 256);                           // 32 KB
    float* w_list          = (float*)(ws + 256 + NEXP * NTOK * 4);       // 32 KB
    __hip_bfloat16* xb     = (__hip_bfloat16*)(ws + 256 + 2 * NEXP * NTOK * 4);       // 2 MB
    __hip_bfloat16* h_buf  = (__hip_bfloat16*)((char*)xb + (size_t)NTOK * DIM * 2);   // 8 MB
    float* ybuf            = (float*)((char*)h_buf + (size_t)NTOK * TOPK * HID * 2);  // 8 MB
    __hip_bfloat16* zrow   = (__hip_bfloat16*)((char*)ybuf + (size_t)NTOK * TOPK * DIM * 4); // 8 KB
    __hip_bfloat16* wgb    = (__hip_bfloat16*)((char*)zrow + 8192);                   // 32 MB
    __hip_bfloat16* wub    = (__hip_bfloat16*)((char*)wgb + (size_t)NEXP * HID * DIM * 2);  // 32 MB

    const int W4 = NEXP * HID * DIM / 4;   // f32x4 chunks per gate/up tensor

    hipMemsetAsync(counts, 0, NEXP * sizeof(int), stream);
    hipMemsetAsync(zrow, 0, HID * sizeof(__hip_bfloat16), stream);
    wcvt_kernel<<<2048, 256, 0, stream>>>(wg, wgb, W4);
    wcvt_kernel<<<2048, 256, 0, stream>>>(wu, wub, W4);
    router_kernel<<<NTOK, 64, 0, stream>>>(x, rw, xb, counts, slot_list, w_list);
    gateup_mfma<<<1024, 256, 0, stream>>>(xb, wgb, wub, counts, slot_list, w_list, zrow, h_buf);
    down_mfma<<<512, 256, 0, stream>>>(h_buf, wd, counts, slot_list, zrow, ybuf);
    combine_kernel<<<NTOK * DIM / 4 / 256, 256, 0, stream>>>(ybuf, out);
}